// Round 11
// baseline (104.966 us; speedup 1.0000x reference)
//
#include <hip/hip_runtime.h>
#include <hip/hip_bf16.h>

#define G_TOTAL 8192        // B*S = 8*1024
#define K_PTS   32
#define TOTAL   133         // 129 rbf + 1 curv + 3 lap
#define OUTD    384
#define NBLK    (G_TOTAL/4) // 2048 blocks, 4 waves each, 1 group/wave

typedef __bf16 bf16x8 __attribute__((ext_vector_type(8)));
typedef float  f32x4  __attribute__((ext_vector_type(4)));

// ---------------- pack W (+bias as row 133) into bf16 MFMA fragment layout --
// wf[((ks*24 + nt)*64 + lane)*8 + j] = Wpad[k = ks*32 + (lane>>4)*8 + j][col = nt*16 + (lane&15)]
__global__ void wprep_kernel(const float* __restrict__ W,
                             const float* __restrict__ bias,
                             __bf16* __restrict__ wf) {
    int idx = blockIdx.x * blockDim.x + threadIdx.x;
    if (idx >= 5*24*64*8) return;
    const int j    = idx & 7;
    const int lane = (idx >> 3) & 63;
    const int tile = idx >> 9;
    const int nt   = tile % 24;
    const int ks   = tile / 24;
    const int k    = ks*32 + ((lane >> 4) << 3) + j;
    const int col  = nt*16 + (lane & 15);
    float v = 0.0f;
    if (k < TOTAL)       v = W[k*OUTD + col];
    else if (k == TOTAL) v = bias[col];
    wf[idx] = (__bf16)v;
}

// ---------------- main: r9 structure (wave-per-group, fused stats, nt stores,
// XCD swizzle) with 512-B-segment epilogue: chunk = 8 N-tiles x half-points,
// bounce 16 rows x 512 B per pass (same 8 KB/wave, same occupancy).
__global__ __launch_bounds__(256, 4)
void main_kernel(const float* __restrict__ xyz,
                 const float* __restrict__ nxyz,
                 const __bf16* __restrict__ wf,
                 float* __restrict__ out) {
    __shared__ float lbuf[4][2048];   // per-wave: 16 rows x 128 floats (8 KB)
    const int lane = threadIdx.x & 63;
    const int wave = threadIdx.x >> 6;
    // XCD swizzle (bijective, 2048 % 8 == 0)
    const int swz  = (blockIdx.x & 7) * (NBLK >> 3) + (blockIdx.x >> 3);
    const int g    = __builtin_amdgcn_readfirstlane(swz * 4 + wave);
    const int pt   = lane & 15;        // point index within half (C^T column)
    const int hi   = lane >> 4;        // k-slice / channel-quad selector

    // ---- fused per-group stats: lanes 0..31 hold one neighbor point ----
    const float* ng = nxyz + (size_t)g * (K_PTS * 3);
    float nx = 0.f, ny = 0.f, nz = 0.f;
    if (lane < K_PTS) {
        nx = ng[lane*3 + 0]; ny = ng[lane*3 + 1]; nz = ng[lane*3 + 2];
    }
    float sx = nx, sy = ny, sz = nz;
    #pragma unroll
    for (int m = 32; m; m >>= 1) {
        sx += __shfl_xor(sx, m);
        sy += __shfl_xor(sy, m);
        sz += __shfl_xor(sz, m);
    }
    const float mg0 = sx * (1.0f/K_PTS), mg1 = sy * (1.0f/K_PTS), mg2 = sz * (1.0f/K_PTS);
    float cxx=0.f, cxy=0.f, cxz=0.f, cyy=0.f, cyz=0.f, czz=0.f;
    if (lane < K_PTS) {
        const float a = nx - mg0, b = ny - mg1, c = nz - mg2;
        cxx = a*a; cxy = a*b; cxz = a*c;
        cyy = b*b; cyz = b*c; czz = c*c;
    }
    #pragma unroll
    for (int m = 32; m; m >>= 1) {
        cxx += __shfl_xor(cxx, m); cxy += __shfl_xor(cxy, m);
        cxz += __shfl_xor(cxz, m); cyy += __shfl_xor(cyy, m);
        cyz += __shfl_xor(cyz, m); czz += __shfl_xor(czz, m);
    }
    {
        const float inv = 1.0f/(K_PTS-1);
        cxx*=inv; cxy*=inv; cxz*=inv; cyy*=inv; cyz*=inv; czz*=inv;
    }
    float cg;
    {
        const float tr = cxx + cyy + czz;
        const float q  = tr * (1.0f/3.0f);
        const float p1 = cxy*cxy + cxz*cxz + cyz*cyz;
        float eigmin;
        if (p1 < 1e-30f) {
            eigmin = fminf(fminf(cxx, cyy), czz);
        } else {
            const float a00 = cxx-q, a11 = cyy-q, a22 = czz-q;
            const float p2 = a00*a00 + a11*a11 + a22*a22 + 2.0f*p1;
            const float pp = sqrtf(p2 * (1.0f/6.0f));
            const float ip = 1.0f/pp;
            const float b00=a00*ip, b11=a11*ip, b22=a22*ip;
            const float b01=cxy*ip, b02=cxz*ip, b12=cyz*ip;
            float detB = b00*(b11*b22 - b12*b12)
                       - b01*(b01*b22 - b12*b02)
                       + b02*(b01*b12 - b11*b02);
            float r = 0.5f * detB;
            r = fminf(1.0f, fmaxf(-1.0f, r));
            const float phi = acosf(r) * (1.0f/3.0f);
            eigmin = q + 2.0f*pp*__cosf(phi + 2.0943951023931953f); // smallest root
        }
        cg = eigmin / (tr + 1e-6f);
    }

    // ---- per-lane sample coords ----
    const float* xg = xyz + (size_t)g * (K_PTS * 3);
    const float xA0 = xg[pt*3 + 0], xA1 = xg[pt*3 + 1], xA2 = xg[pt*3 + 2];
    const float xB0 = xg[(pt+16)*3 + 0], xB1 = xg[(pt+16)*3 + 1], xB2 = xg[(pt+16)*3 + 2];

    // Build F-fragments: lane holds F[pt][k = ks*32 + hi*8 + j].
    bf16x8 fA[5], fB[5];
    #pragma unroll
    for (int ks = 0; ks < 4; ++ks) {
        #pragma unroll
        for (int j = 0; j < 8; ++j) {
            const int   k  = ks*32 + hi*8 + j;          // < 128: always RBF
            const int   d  = (k * 1525) >> 16;          // k / 43
            const float f  = (float)(k - d*43);
            const float fv = (f + 1.0f) * (1.0f/22.0f) - 1.0f;
            const float sA = (d==0) ? xA0 : ((d==1) ? xA1 : xA2);
            const float sB = (d==0) ? xB0 : ((d==1) ? xB1 : xB2);
            const float tA = sA - fv, tB = sB - fv;
            fA[ks][j] = (__bf16)__expf(-2.0f*tA*tA);
            fB[ks][j] = (__bf16)__expf(-2.0f*tB*tB);
        }
    }
    {   // ks = 4: rbf(128) | curv | lap | bias-1 | zeros
        bf16x8 a4, b4;
        #pragma unroll
        for (int j = 0; j < 8; ++j) { a4[j] = (__bf16)0.0f; b4[j] = (__bf16)0.0f; }
        if (hi == 0) {
            const float fv = 43.0f*(1.0f/22.0f) - 1.0f;   // k=128 -> d=2, f=42
            const float tA = xA2 - fv, tB = xB2 - fv;
            a4[0] = (__bf16)__expf(-2.0f*tA*tA);
            b4[0] = (__bf16)__expf(-2.0f*tB*tB);
            a4[1] = (__bf16)cg;              b4[1] = (__bf16)cg;
            a4[2] = (__bf16)fabsf(xA0-mg0);  b4[2] = (__bf16)fabsf(xB0-mg0);
            a4[3] = (__bf16)fabsf(xA1-mg1);  b4[3] = (__bf16)fabsf(xB1-mg1);
            a4[4] = (__bf16)fabsf(xA2-mg2);  b4[4] = (__bf16)fabsf(xB2-mg2);
            a4[5] = (__bf16)1.0f;            b4[5] = (__bf16)1.0f;
        }
        fA[4] = a4; fB[4] = b4;
    }

    float* myb  = lbuf[wave];
    float* outg = out + (size_t)g * (K_PTS * OUTD);

    // 3 chunks of 8 N-tiles (128 channels); each chunk in 2 half-point passes.
    // Bounce: 16 rows x 32 f32x4 slots; write slot' = q ^ (pt&7), q = nl*4+hi.
    for (int c = 0; c < 3; ++c) {
        // ---- pass A: points 0..15 ----
        #pragma unroll
        for (int nl = 0; nl < 8; ++nl) {
            const int nt = c*8 + nl;
            f32x4 a0 = {};
            #pragma unroll
            for (int ks = 0; ks < 5; ++ks) {
                const bf16x8 w = *reinterpret_cast<const bf16x8*>(
                    wf + (((size_t)(ks*24 + nt)) * 64 + lane) * 8);
                a0 = __builtin_amdgcn_mfma_f32_16x16x32_bf16(w, fA[ks], a0, 0, 0, 0);
            }
            const int sp = (nl*4 + hi) ^ (pt & 7);
            *reinterpret_cast<f32x4*>(&myb[pt*128 + sp*4]) = a0;
        }
        #pragma unroll
        for (int i = 0; i < 8; ++i) {
            const int flat = i*64 + lane;      // 0..511
            const int r    = flat >> 5;        // row 0..15
            const int sl   = flat & 31;        // chunk-local f32x4 index
            const f32x4 v = *reinterpret_cast<const f32x4*>(
                &myb[r*128 + ((sl ^ (r & 7)) * 4)]);
            __builtin_nontemporal_store(v,
                reinterpret_cast<f32x4*>(outg + r*OUTD + c*128 + sl*4));
        }
        // ---- pass B: points 16..31 ----
        #pragma unroll
        for (int nl = 0; nl < 8; ++nl) {
            const int nt = c*8 + nl;
            f32x4 a1 = {};
            #pragma unroll
            for (int ks = 0; ks < 5; ++ks) {
                const bf16x8 w = *reinterpret_cast<const bf16x8*>(
                    wf + (((size_t)(ks*24 + nt)) * 64 + lane) * 8);
                a1 = __builtin_amdgcn_mfma_f32_16x16x32_bf16(w, fB[ks], a1, 0, 0, 0);
            }
            const int sp = (nl*4 + hi) ^ (pt & 7);
            *reinterpret_cast<f32x4*>(&myb[pt*128 + sp*4]) = a1;
        }
        #pragma unroll
        for (int i = 0; i < 8; ++i) {
            const int flat = i*64 + lane;
            const int r    = flat >> 5;
            const int sl   = flat & 31;
            const f32x4 v = *reinterpret_cast<const f32x4*>(
                &myb[r*128 + ((sl ^ (r & 7)) * 4)]);
            __builtin_nontemporal_store(v,
                reinterpret_cast<f32x4*>(outg + (r+16)*OUTD + c*128 + sl*4));
        }
    }
}

extern "C" void kernel_launch(void* const* d_in, const int* in_sizes, int n_in,
                              void* d_out, int out_size, void* d_ws, size_t ws_size,
                              hipStream_t stream) {
    const float* xyz  = (const float*)d_in[0];
    const float* nxyz = (const float*)d_in[1];
    const float* W    = (const float*)d_in[2];
    const float* bias = (const float*)d_in[3];
    float* out = (float*)d_out;

    __bf16* wf = (__bf16*)d_ws;   // 61440 * 2 = 120 KB packed weight+bias

    wprep_kernel<<<(5*24*64*8 + 255)/256, 256, 0, stream>>>(W, bias, wf);
    main_kernel<<<NBLK, 256, 0, stream>>>(xyz, nxyz, wf, out);
}

// Round 12
// 92.239 us; speedup vs baseline: 1.1380x; 1.1380x over previous
//
#include <hip/hip_runtime.h>
#include <hip/hip_bf16.h>

#define G_TOTAL 8192        // B*S = 8*1024
#define K_PTS   32
#define TOTAL   133         // 129 rbf + 1 curv + 3 lap
#define OUTD    384
#define NBLK    (G_TOTAL/4) // 2048 blocks, 4 waves each, 1 group/wave

typedef __bf16 bf16x8 __attribute__((ext_vector_type(8)));
typedef float  f32x4  __attribute__((ext_vector_type(4)));

// ---------------- pack W (+bias as row 133) into bf16 MFMA fragment layout --
// wf[((ks*24 + nt)*64 + lane)*8 + j] = Wpad[k = ks*32 + (lane>>4)*8 + j][col = nt*16 + (lane&15)]
__global__ void wprep_kernel(const float* __restrict__ W,
                             const float* __restrict__ bias,
                             __bf16* __restrict__ wf) {
    int idx = blockIdx.x * blockDim.x + threadIdx.x;
    if (idx >= 5*24*64*8) return;
    const int j    = idx & 7;
    const int lane = (idx >> 3) & 63;
    const int tile = idx >> 9;
    const int nt   = tile % 24;
    const int ks   = tile / 24;
    const int k    = ks*32 + ((lane >> 4) << 3) + j;
    const int col  = nt*16 + (lane & 15);
    float v = 0.0f;
    if (k < TOTAL)       v = W[k*OUTD + col];
    else if (k == TOTAL) v = bias[col];
    wf[idx] = (__bf16)v;
}

// ---------------- main (r4 body): wave-per-group; fused in-wave stats; ------
// in-register F-fragments; LDS-bounce epilogue; nt coalesced 256-B stores.
// + bijective XCD-aware block swizzle (2048 % 8 == 0).  [best measured: 93.0 us]
__global__ __launch_bounds__(256, 4)
void main_kernel(const float* __restrict__ xyz,
                 const float* __restrict__ nxyz,
                 const __bf16* __restrict__ wf,
                 float* __restrict__ out) {
    __shared__ float lbuf[4][2048];   // per-wave: 32 rows x 16 slots x 4 floats (8 KB)
    const int lane = threadIdx.x & 63;
    const int wave = threadIdx.x >> 6;
    // XCD swizzle: default assignment is round-robin (blockIdx % 8 = XCD).
    // Remap so each XCD owns a contiguous chunk of the group space.
    const int swz  = (blockIdx.x & 7) * (NBLK >> 3) + (blockIdx.x >> 3);
    const int g    = __builtin_amdgcn_readfirstlane(swz * 4 + wave);
    const int pt   = lane & 15;        // point index (C^T column)
    const int hi   = lane >> 4;        // k-slice / channel-quad selector

    // ---- fused per-group stats: lanes 0..31 hold one neighbor point ----
    const float* ng = nxyz + (size_t)g * (K_PTS * 3);
    float nx = 0.f, ny = 0.f, nz = 0.f;
    if (lane < K_PTS) {
        nx = ng[lane*3 + 0]; ny = ng[lane*3 + 1]; nz = ng[lane*3 + 2];
    }
    float sx = nx, sy = ny, sz = nz;
    #pragma unroll
    for (int m = 32; m; m >>= 1) {
        sx += __shfl_xor(sx, m);
        sy += __shfl_xor(sy, m);
        sz += __shfl_xor(sz, m);
    }
    const float mg0 = sx * (1.0f/K_PTS), mg1 = sy * (1.0f/K_PTS), mg2 = sz * (1.0f/K_PTS);
    float cxx=0.f, cxy=0.f, cxz=0.f, cyy=0.f, cyz=0.f, czz=0.f;
    if (lane < K_PTS) {
        const float a = nx - mg0, b = ny - mg1, c = nz - mg2;
        cxx = a*a; cxy = a*b; cxz = a*c;
        cyy = b*b; cyz = b*c; czz = c*c;
    }
    #pragma unroll
    for (int m = 32; m; m >>= 1) {
        cxx += __shfl_xor(cxx, m); cxy += __shfl_xor(cxy, m);
        cxz += __shfl_xor(cxz, m); cyy += __shfl_xor(cyy, m);
        cyz += __shfl_xor(cyz, m); czz += __shfl_xor(czz, m);
    }
    {
        const float inv = 1.0f/(K_PTS-1);
        cxx*=inv; cxy*=inv; cxz*=inv; cyy*=inv; cyz*=inv; czz*=inv;
    }
    float cg;
    {
        const float tr = cxx + cyy + czz;
        const float q  = tr * (1.0f/3.0f);
        const float p1 = cxy*cxy + cxz*cxz + cyz*cyz;
        float eigmin;
        if (p1 < 1e-30f) {
            eigmin = fminf(fminf(cxx, cyy), czz);
        } else {
            const float a00 = cxx-q, a11 = cyy-q, a22 = czz-q;
            const float p2 = a00*a00 + a11*a11 + a22*a22 + 2.0f*p1;
            const float pp = sqrtf(p2 * (1.0f/6.0f));
            const float ip = 1.0f/pp;
            const float b00=a00*ip, b11=a11*ip, b22=a22*ip;
            const float b01=cxy*ip, b02=cxz*ip, b12=cyz*ip;
            float detB = b00*(b11*b22 - b12*b12)
                       - b01*(b01*b22 - b12*b02)
                       + b02*(b01*b12 - b11*b02);
            float r = 0.5f * detB;
            r = fminf(1.0f, fmaxf(-1.0f, r));
            const float phi = acosf(r) * (1.0f/3.0f);
            eigmin = q + 2.0f*pp*__cosf(phi + 2.0943951023931953f); // smallest root
        }
        cg = eigmin / (tr + 1e-6f);
    }

    // ---- per-lane sample coords ----
    const float* xg = xyz + (size_t)g * (K_PTS * 3);
    const float xA0 = xg[pt*3 + 0], xA1 = xg[pt*3 + 1], xA2 = xg[pt*3 + 2];
    const float xB0 = xg[(pt+16)*3 + 0], xB1 = xg[(pt+16)*3 + 1], xB2 = xg[(pt+16)*3 + 2];

    // Build F-fragments: lane holds F[pt][k = ks*32 + hi*8 + j].
    bf16x8 fA[5], fB[5];
    #pragma unroll
    for (int ks = 0; ks < 4; ++ks) {
        #pragma unroll
        for (int j = 0; j < 8; ++j) {
            const int   k  = ks*32 + hi*8 + j;          // < 128: always RBF
            const int   d  = (k * 1525) >> 16;          // k / 43
            const float f  = (float)(k - d*43);
            const float fv = (f + 1.0f) * (1.0f/22.0f) - 1.0f;
            const float sA = (d==0) ? xA0 : ((d==1) ? xA1 : xA2);
            const float sB = (d==0) ? xB0 : ((d==1) ? xB1 : xB2);
            const float tA = sA - fv, tB = sB - fv;
            fA[ks][j] = (__bf16)__expf(-2.0f*tA*tA);
            fB[ks][j] = (__bf16)__expf(-2.0f*tB*tB);
        }
    }
    {   // ks = 4: rbf(128) | curv | lap | bias-1 | zeros
        bf16x8 a4, b4;
        #pragma unroll
        for (int j = 0; j < 8; ++j) { a4[j] = (__bf16)0.0f; b4[j] = (__bf16)0.0f; }
        if (hi == 0) {
            const float fv = 43.0f*(1.0f/22.0f) - 1.0f;   // k=128 -> d=2, f=42
            const float tA = xA2 - fv, tB = xB2 - fv;
            a4[0] = (__bf16)__expf(-2.0f*tA*tA);
            b4[0] = (__bf16)__expf(-2.0f*tB*tB);
            a4[1] = (__bf16)cg;              b4[1] = (__bf16)cg;
            a4[2] = (__bf16)fabsf(xA0-mg0);  b4[2] = (__bf16)fabsf(xB0-mg0);
            a4[3] = (__bf16)fabsf(xA1-mg1);  b4[3] = (__bf16)fabsf(xB1-mg1);
            a4[4] = (__bf16)fabsf(xA2-mg2);  b4[4] = (__bf16)fabsf(xB2-mg2);
            a4[5] = (__bf16)1.0f;            b4[5] = (__bf16)1.0f;
        }
        fA[4] = a4; fB[4] = b4;
    }

    float* myb  = lbuf[wave];
    float* outg = out + (size_t)g * (K_PTS * OUTD);

    // 6 chunks of 4 N-tiles (64 channels each)
    for (int c = 0; c < 6; ++c) {
        f32x4 accA[4], accB[4];
        #pragma unroll
        for (int nl = 0; nl < 4; ++nl) {
            const int nt = c*4 + nl;
            f32x4 a0 = {}, a1 = {};
            #pragma unroll
            for (int ks = 0; ks < 5; ++ks) {
                const bf16x8 w = *reinterpret_cast<const bf16x8*>(
                    wf + (((size_t)(ks*24 + nt)) * 64 + lane) * 8);
                a0 = __builtin_amdgcn_mfma_f32_16x16x32_bf16(w, fA[ks], a0, 0, 0, 0);
                a1 = __builtin_amdgcn_mfma_f32_16x16x32_bf16(w, fB[ks], a1, 0, 0, 0);
            }
            accA[nl] = a0; accB[nl] = a1;
        }
        // XOR-swizzled per-wave LDS write: row = pt (+16 for B), slot q = nl*4+hi
        #pragma unroll
        for (int nl = 0; nl < 4; ++nl) {
            const int q = nl*4 + hi;
            *reinterpret_cast<f32x4*>(&myb[(pt     )*64 + ((q ^ pt) * 4)]) = accA[nl];
            *reinterpret_cast<f32x4*>(&myb[(pt + 16)*64 + ((q ^ pt) * 4)]) = accB[nl];
        }
        // linear read-back (swizzle-inverted) + coalesced 256-B-per-row nt stores
        #pragma unroll
        for (int i = 0; i < 8; ++i) {
            const int row = i*4 + hi;
            const f32x4 v = *reinterpret_cast<const f32x4*>(
                &myb[row*64 + ((pt ^ (row & 15)) * 4)]);
            __builtin_nontemporal_store(v,
                reinterpret_cast<f32x4*>(outg + row*OUTD + c*64 + pt*4));
        }
    }
}

extern "C" void kernel_launch(void* const* d_in, const int* in_sizes, int n_in,
                              void* d_out, int out_size, void* d_ws, size_t ws_size,
                              hipStream_t stream) {
    const float* xyz  = (const float*)d_in[0];
    const float* nxyz = (const float*)d_in[1];
    const float* W    = (const float*)d_in[2];
    const float* bias = (const float*)d_in[3];
    float* out = (float*)d_out;

    __bf16* wf = (__bf16*)d_ws;   // 61440 * 2 = 120 KB packed weight+bias

    wprep_kernel<<<(5*24*64*8 + 255)/256, 256, 0, stream>>>(W, bias, wf);
    main_kernel<<<NBLK, 256, 0, stream>>>(xyz, nxyz, wf, out);
}